// Round 1
// baseline (462.724 us; speedup 1.0000x reference)
//
#include <hip/hip_runtime.h>
#include <math.h>

#define N_NODES 90
#define KSEL 45
#define DIM 1024
#define BATCH 512

// ---------------------------------------------------------------------------
// Kernel A: per-(b,n) row scores.
// s_sc = dot(x_sc[b,n,:], pool_w); s_fc likewise; wsq = ||pool_w||^2 (fused,
// redundant per block but free — this kernel is HBM-bound on the x reads).
// score = sigmoid(tanh(s_sc/|w|)*mw0 + tanh(s_fc/|w|)*mw1 + mb[n])
// ---------------------------------------------------------------------------
__global__ __launch_bounds__(256) void score_kernel(
    const float* __restrict__ x_sc, const float* __restrict__ x_fc,
    const float* __restrict__ pool_w, const float* __restrict__ multi_w,
    const float* __restrict__ multi_b, float* __restrict__ scores)
{
    const int row = blockIdx.x;            // b*N_NODES + n
    const int tid = threadIdx.x;           // 256 threads, 4 floats each = 1024
    const size_t base = (size_t)row * DIM;

    const float4* a4 = (const float4*)(x_sc + base);
    const float4* b4 = (const float4*)(x_fc + base);
    const float4* w4 = (const float4*)pool_w;

    float4 a = a4[tid];
    float4 b = b4[tid];
    float4 w = w4[tid];

    float dsc = a.x*w.x + a.y*w.y + a.z*w.z + a.w*w.w;
    float dfc = b.x*w.x + b.y*w.y + b.z*w.z + b.w*w.w;
    float wsq = w.x*w.x + w.y*w.y + w.z*w.z + w.w*w.w;

    // wave-64 butterfly reduction, 3 values
    for (int off = 32; off > 0; off >>= 1) {
        dsc += __shfl_down(dsc, off, 64);
        dfc += __shfl_down(dfc, off, 64);
        wsq += __shfl_down(wsq, off, 64);
    }

    __shared__ float s1[4], s2[4], s3[4];
    const int wave = tid >> 6, lane = tid & 63;
    if (lane == 0) { s1[wave] = dsc; s2[wave] = dfc; s3[wave] = wsq; }
    __syncthreads();

    if (tid == 0) {
        float t1 = s1[0] + s1[1] + s1[2] + s1[3];
        float t2 = s2[0] + s2[1] + s2[2] + s2[3];
        float t3 = s3[0] + s3[1] + s3[2] + s3[3];
        float inv_norm = rsqrtf(t3);
        float sc = tanhf(t1 * inv_norm);
        float fc = tanhf(t2 * inv_norm);
        int n = row % N_NODES;
        float z = sc * multi_w[0] + fc * multi_w[1] + multi_b[n];
        // accurate expf (one per row) to keep score ordering faithful to np ref
        scores[row] = 1.0f / (1.0f + expf(-z));
    }
}

// ---------------------------------------------------------------------------
// Kernel B: stable top-K per batch, reproducing argsort(-score) semantics.
// rank(n) = #{j : s[j] > s[n]} + #{j < n : s[j] == s[n]}  (stable tie order)
// Node with rank r < K lands at output slot r.
// ---------------------------------------------------------------------------
__global__ __launch_bounds__(128) void topk_kernel(
    const float* __restrict__ scores, int* __restrict__ idx,
    float* __restrict__ wgt)
{
    const int b = blockIdx.x;
    const int t = threadIdx.x;
    __shared__ float s[N_NODES];
    if (t < N_NODES) s[t] = scores[b * N_NODES + t];
    __syncthreads();
    if (t < N_NODES) {
        float v = s[t];
        int rank = 0;
        #pragma unroll
        for (int j = 0; j < N_NODES; ++j) {
            float u = s[j];
            rank += (u > v) || (u == v && j < t);
        }
        if (rank < KSEL) {
            idx[b * KSEL + rank] = t;
            wgt[b * KSEL + rank] = v;
        }
    }
}

// ---------------------------------------------------------------------------
// Kernel C: gather+scale. One block per output row (b,k); copies the selected
// node row from both x_sc and x_fc, scaled by its score. float4 in/out.
// ---------------------------------------------------------------------------
__global__ __launch_bounds__(256) void gather_kernel(
    const float* __restrict__ x_sc, const float* __restrict__ x_fc,
    const int* __restrict__ idx, const float* __restrict__ wgt,
    float* __restrict__ out)
{
    const int m = blockIdx.x;              // b*KSEL + k
    const int b = m / KSEL;
    const int t = threadIdx.x;

    const int n = idx[m];
    const float w = wgt[m];

    const size_t src = ((size_t)b * N_NODES + n) * DIM;
    const size_t dst = (size_t)m * DIM;

    const float4* a4 = (const float4*)(x_sc + src);
    const float4* b4 = (const float4*)(x_fc + src);
    float4* o1 = (float4*)(out + dst);
    float4* o2 = (float4*)(out + (size_t)BATCH * KSEL * DIM + dst);

    float4 a = a4[t];
    a.x *= w; a.y *= w; a.z *= w; a.w *= w;
    o1[t] = a;
    float4 c = b4[t];
    c.x *= w; c.y *= w; c.z *= w; c.w *= w;
    o2[t] = c;
}

extern "C" void kernel_launch(void* const* d_in, const int* in_sizes, int n_in,
                              void* d_out, int out_size, void* d_ws, size_t ws_size,
                              hipStream_t stream) {
    const float* x_sc    = (const float*)d_in[0];
    const float* x_fc    = (const float*)d_in[1];
    const float* pool_w  = (const float*)d_in[2];
    const float* multi_w = (const float*)d_in[3];
    const float* multi_b = (const float*)d_in[4];
    float* out = (float*)d_out;

    // workspace layout: scores[B*N] | wgt[B*K] | idx[B*K]  (< 400 KB)
    float* scores = (float*)d_ws;
    float* wgt    = scores + BATCH * N_NODES;
    int*   idx    = (int*)(wgt + BATCH * KSEL);

    score_kernel<<<BATCH * N_NODES, 256, 0, stream>>>(
        x_sc, x_fc, pool_w, multi_w, multi_b, scores);
    topk_kernel<<<BATCH, 128, 0, stream>>>(scores, idx, wgt);
    gather_kernel<<<BATCH * KSEL, 256, 0, stream>>>(
        x_sc, x_fc, idx, wgt, out);
}